// Round 11
// baseline (42.540 us; speedup 1.0000x reference)
//
#include <hip/hip_runtime.h>

// Problem constants (B=64, N=600, C=256)
#define B_DIM 64
#define N_NODES 600
#define C_DIM 256
#define NV4 (N_NODES / 4)              // 150 float4 per A row
#define ROWTILE 32
#define BLK_PER_B ((N_NODES + ROWTILE - 1) / ROWTILE)   // 19
#define GBLOCKS (B_DIM * BLK_PER_B)    // 1216 -> 4.75 blocks/CU, one generation
#define SBLOCKS (B_DIM * N_NODES / 32) // 1200 (32 rows per block, 8 per wave)

constexpr float kThr = 0.003f;   // THRESHOLD
constexpr float kEps = 1e-7f;    // EPS

// ---------------------------------------------------------------------------
// K1: scores = x . W -> alpha_pre = exp(score)*mask.
// Each wave handles 8 CONSECUTIVE rows (MLP=8). 1200 blocks = 18.75 waves/CU:
// the whole kernel is ONE co-resident generation (no scheduling tail).
// Per-row summation order BIT-IDENTICAL to R6/R10 (threshold numerics).
// ---------------------------------------------------------------------------
__global__ __launch_bounds__(256)
void k_scores(const float* __restrict__ x,
              const float* __restrict__ W,
              const int* __restrict__ mask,
              float* __restrict__ alpha_pre) {
  const int wave = threadIdx.x >> 6;
  const int lane = threadIdx.x & 63;
  const int row0 = (blockIdx.x * 4 + wave) * 8;   // 8 consecutive rows
  const float4 wv = reinterpret_cast<const float4*>(W)[lane];
  const float4* xr = reinterpret_cast<const float4*>(x) + (size_t)row0 * 64 + lane;

  float4 v[8];
  #pragma unroll
  for (int r = 0; r < 8; ++r) v[r] = xr[r * 64];

  float s[8];
  #pragma unroll
  for (int r = 0; r < 8; ++r)
    s[r] = v[r].x * wv.x + v[r].y * wv.y + v[r].z * wv.z + v[r].w * wv.w;

  #pragma unroll
  for (int off = 32; off > 0; off >>= 1) {
    #pragma unroll
    for (int r = 0; r < 8; ++r) s[r] += __shfl_down(s[r], off, 64);
  }
  if (lane == 0) {
    const int4 m0 = *reinterpret_cast<const int4*>(mask + row0);
    const int4 m1 = *reinterpret_cast<const int4*>(mask + row0 + 4);
    float4 a0, a1;
    a0.x = m0.x ? expf(s[0]) : 0.0f;
    a0.y = m0.y ? expf(s[1]) : 0.0f;
    a0.z = m0.z ? expf(s[2]) : 0.0f;
    a0.w = m0.w ? expf(s[3]) : 0.0f;
    a1.x = m1.x ? expf(s[4]) : 0.0f;
    a1.y = m1.y ? expf(s[5]) : 0.0f;
    a1.z = m1.z ? expf(s[6]) : 0.0f;
    a1.w = m1.w ? expf(s[7]) : 0.0f;
    *reinterpret_cast<float4*>(alpha_pre + row0)     = a0;
    *reinterpret_cast<float4*>(alpha_pre + row0 + 4) = a1;
  }
}

// ---------------------------------------------------------------------------
// K2: one block per (batch, 32-row output tile) -> 1216 blocks, all
// co-resident (4.75 blocks/CU vs 8 cap): no scheduling tail, compact
// prologue paid half as often as R10. Block-local redundant compact
// (bit-exact 1024-tree emulation, validated R4/R6). Plain stores (R8: nt
// hurt). Heavy path identical to R10.
// ---------------------------------------------------------------------------
__global__ __launch_bounds__(256)
void k_gather(const float* __restrict__ x,
              const float* __restrict__ A,
              const float* __restrict__ alpha_pre,
              float* __restrict__ xo,
              float* __restrict__ Ao,
              float* __restrict__ mo) {
  const int bid  = blockIdx.x;
  const int b    = bid / BLK_PER_B;
  const int i0   = (bid % BLK_PER_B) * ROWTILE;
  const int t    = threadIdx.x;
  const int wave = t >> 6;
  const int lane = t & 63;

  __shared__ __align__(16) float sAP[N_NODES];
  __shared__ float fs[256];
  __shared__ int   wtot[4];
  __shared__ int   sidx[N_NODES];

  // ---- local compact (identical numerics to R6/R10) ----
  {
    const float4* ab4 = reinterpret_cast<const float4*>(alpha_pre + b * N_NODES);
    float4* sAP4 = reinterpret_cast<float4*>(sAP);
    if (t < NV4) sAP4[t] = ab4[t];
  }
  __syncthreads();

  float v = sAP[t];
  if (t < N_NODES - 512) v += sAP[t + 512];   // level 512
  v += sAP[t + 256];                          // level 256 (t+256 < 512 < 600)
  fs[t] = v;
  __syncthreads();
  #pragma unroll
  for (int off = 128; off > 0; off >>= 1) {
    if (t < off) fs[t] += fs[t + off];
    __syncthreads();
  }
  const float S = fs[0];

  int k3[3] = {0, 0, 0};
  int c = 0;
  const int n0 = t * 3;
  if (t < 200) {
    #pragma unroll
    for (int k = 0; k < 3; ++k) {
      const float a = sAP[n0 + k] / (S + kEps);
      k3[k] = (a > kThr) ? 1 : 0;   // mask==0 => ap==0 => a==0 => not kept
      c += k3[k];
    }
  }
  int incl = c;
  #pragma unroll
  for (int off = 1; off < 64; off <<= 1) {
    const int u = __shfl_up(incl, off, 64);
    if (lane >= off) incl += u;
  }
  if (lane == 63) wtot[wave] = incl;
  __syncthreads();
  int offtot = 0, K = 0;
  #pragma unroll
  for (int w2 = 0; w2 < 4; ++w2) {
    const int u = wtot[w2];
    if (w2 < wave) offtot += u;
    K += u;
  }
  int run = incl - c + offtot;       // kept nodes before n0
  if (t < 200) {
    #pragma unroll
    for (int k = 0; k < 3; ++k) {
      const int n = n0 + k;
      if (k3[k]) { sidx[run] = n; ++run; }
      else       { sidx[K + (n - run)] = n; }
    }
  }
  __syncthreads();

  if (i0 == 0) {
    for (int n = t; n < N_NODES; n += 256)
      mo[b * N_NODES + n] = (n < K) ? 1.0f : 0.0f;
  }

  const float Sd = S + kEps;
  const int kq = K >> 2;             // float4s fully inside [0,K)
  const float* xb  = x  + (size_t)b * N_NODES * C_DIM;
  float*       xob = xo + (size_t)b * N_NODES * C_DIM;
  const float* Ab  = A  + (size_t)b * N_NODES * N_NODES;
  float*       Aob = Ao + (size_t)b * N_NODES * N_NODES;

  for (int ii = wave; ii < ROWTILE; ii += 4) {
    const int i = i0 + ii;
    if (i >= N_NODES) break;
    const int src = sidx[i];

    // ---- x row: xo[b,i,:] = x[b,src,:] * alpha[src] ----
    const float a = sAP[src] / Sd;
    float4 xv = reinterpret_cast<const float4*>(xb + (size_t)src * C_DIM)[lane];
    xv.x *= a; xv.y *= a; xv.z *= a; xv.w *= a;
    reinterpret_cast<float4*>(xob + (size_t)i * C_DIM)[lane] = xv;

    // ---- A row ----
    float4* orow = reinterpret_cast<float4*>(Aob + (size_t)i * N_NODES);
    if (i < K) {
      const float* Arow = Ab + (size_t)src * N_NODES;
      for (int j4 = lane; j4 < NV4; j4 += 64) {
        float4 w4 = {0.f, 0.f, 0.f, 0.f};
        if (j4 < kq) {
          const int j = j4 * 4;
          w4.x = Arow[sidx[j + 0]];
          w4.y = Arow[sidx[j + 1]];
          w4.z = Arow[sidx[j + 2]];
          w4.w = Arow[sidx[j + 3]];
        } else if (j4 == kq) {
          const int j = j4 * 4;
          if (j + 0 < K) w4.x = Arow[sidx[j + 0]];
          if (j + 1 < K) w4.y = Arow[sidx[j + 1]];
          if (j + 2 < K) w4.z = Arow[sidx[j + 2]];
        }
        orow[j4] = w4;
      }
    } else {
      const float4 z = {0.f, 0.f, 0.f, 0.f};
      #pragma unroll 3
      for (int j4 = lane; j4 < NV4; j4 += 64) orow[j4] = z;
    }
  }
}

// ---------------------------------------------------------------------------
extern "C" void kernel_launch(void* const* d_in, const int* in_sizes, int n_in,
                              void* d_out, int out_size, void* d_ws, size_t ws_size,
                              hipStream_t stream) {
  const float* x    = (const float*)d_in[0];
  const float* A    = (const float*)d_in[1];
  const int*   mask = (const int*)d_in[2];
  const float* W    = (const float*)d_in[3];

  const size_t BN = (size_t)B_DIM * N_NODES;

  float* xo = (float*)d_out;                       // (B,N,C)
  float* Ao = xo + BN * C_DIM;                     // (B,N,N)
  float* mo = Ao + BN * N_NODES;                   // (B,N) as 0.0/1.0

  float* alpha_pre = (float*)d_ws;                 // B*N floats

  k_scores<<<SBLOCKS, 256, 0, stream>>>(x, W, mask, alpha_pre);
  k_gather<<<GBLOCKS, 256, 0, stream>>>(x, A, alpha_pre, xo, Ao, mo);
}

// Round 12
// 39.837 us; speedup vs baseline: 1.0678x; 1.0678x over previous
//
#include <hip/hip_runtime.h>

// Problem constants (B=64, N=600, C=256)
#define B_DIM 64
#define N_NODES 600
#define C_DIM 256
#define NV4 (N_NODES / 4)              // 150 float4 per A row
#define ROWTILE 16
#define BLK_PER_B ((N_NODES + ROWTILE - 1) / ROWTILE)   // 38
#define GBLOCKS (B_DIM * BLK_PER_B)    // 2432
#define SBLOCKS (B_DIM * N_NODES / 16) // 2400 (16 rows per block, 4 per wave)

constexpr float kThr = 0.003f;   // THRESHOLD
constexpr float kEps = 1e-7f;    // EPS

// ---------------------------------------------------------------------------
// K1: scores = x . W -> alpha_pre = exp(score)*mask.
// Each wave handles 4 CONSECUTIVE rows: 4 independent float4 loads in flight
// (MLP=4), then 4 shuffle trees. Per-row summation order BIT-IDENTICAL to
// the R6-passing version — numerics are load-bearing for the threshold.
// (R11 lesson: MLP=8 / fewer blocks regressed; this config is the optimum.)
// ---------------------------------------------------------------------------
__global__ __launch_bounds__(256)
void k_scores(const float* __restrict__ x,
              const float* __restrict__ W,
              const int* __restrict__ mask,
              float* __restrict__ alpha_pre) {
  const int wave = threadIdx.x >> 6;
  const int lane = threadIdx.x & 63;
  const int row0 = (blockIdx.x * 4 + wave) * 4;   // 4 consecutive rows
  const float4 wv = reinterpret_cast<const float4*>(W)[lane];
  const float4* xr = reinterpret_cast<const float4*>(x) + (size_t)row0 * 64 + lane;

  const float4 v0 = xr[0];
  const float4 v1 = xr[64];
  const float4 v2 = xr[128];
  const float4 v3 = xr[192];

  float s0 = v0.x * wv.x + v0.y * wv.y + v0.z * wv.z + v0.w * wv.w;
  float s1 = v1.x * wv.x + v1.y * wv.y + v1.z * wv.z + v1.w * wv.w;
  float s2 = v2.x * wv.x + v2.y * wv.y + v2.z * wv.z + v2.w * wv.w;
  float s3 = v3.x * wv.x + v3.y * wv.y + v3.z * wv.z + v3.w * wv.w;

  #pragma unroll
  for (int off = 32; off > 0; off >>= 1) {
    s0 += __shfl_down(s0, off, 64);
    s1 += __shfl_down(s1, off, 64);
    s2 += __shfl_down(s2, off, 64);
    s3 += __shfl_down(s3, off, 64);
  }
  if (lane == 0) {
    const int4 m4 = *reinterpret_cast<const int4*>(mask + row0);
    float4 ap;
    ap.x = m4.x ? expf(s0) : 0.0f;
    ap.y = m4.y ? expf(s1) : 0.0f;
    ap.z = m4.z ? expf(s2) : 0.0f;
    ap.w = m4.w ? expf(s3) : 0.0f;
    *reinterpret_cast<float4*>(alpha_pre + row0) = ap;
  }
}

// ---------------------------------------------------------------------------
// K2: one block per (batch, 16-row output tile). Each block redundantly
// recomputes the batch compaction from alpha_pre (bit-exact 1024-tree
// emulation, validated R4/R6). Then x-row gather + A-row writes.
// ROWTILE=16 (R11: 32 regressed), plain stores (R8: nt regressed),
// direct global gather (R9: LDS staging neutral).
// ---------------------------------------------------------------------------
__global__ __launch_bounds__(256)
void k_gather(const float* __restrict__ x,
              const float* __restrict__ A,
              const float* __restrict__ alpha_pre,
              float* __restrict__ xo,
              float* __restrict__ Ao,
              float* __restrict__ mo) {
  const int bid  = blockIdx.x;
  const int b    = bid / BLK_PER_B;
  const int i0   = (bid % BLK_PER_B) * ROWTILE;
  const int t    = threadIdx.x;
  const int wave = t >> 6;
  const int lane = t & 63;

  __shared__ __align__(16) float sAP[N_NODES];
  __shared__ float fs[256];
  __shared__ int   wtot[4];
  __shared__ int   sidx[N_NODES];

  // ---- local compact (identical numerics to R6/R10) ----
  {
    const float4* ab4 = reinterpret_cast<const float4*>(alpha_pre + b * N_NODES);
    float4* sAP4 = reinterpret_cast<float4*>(sAP);
    if (t < NV4) sAP4[t] = ab4[t];
  }
  __syncthreads();

  float v = sAP[t];
  if (t < N_NODES - 512) v += sAP[t + 512];   // level 512
  v += sAP[t + 256];                          // level 256 (t+256 < 512 < 600)
  fs[t] = v;
  __syncthreads();
  #pragma unroll
  for (int off = 128; off > 0; off >>= 1) {
    if (t < off) fs[t] += fs[t + off];
    __syncthreads();
  }
  const float S = fs[0];

  int k3[3] = {0, 0, 0};
  int c = 0;
  const int n0 = t * 3;
  if (t < 200) {
    #pragma unroll
    for (int k = 0; k < 3; ++k) {
      const float a = sAP[n0 + k] / (S + kEps);
      k3[k] = (a > kThr) ? 1 : 0;   // mask==0 => ap==0 => a==0 => not kept
      c += k3[k];
    }
  }
  int incl = c;
  #pragma unroll
  for (int off = 1; off < 64; off <<= 1) {
    const int u = __shfl_up(incl, off, 64);
    if (lane >= off) incl += u;
  }
  if (lane == 63) wtot[wave] = incl;
  __syncthreads();
  int offtot = 0, K = 0;
  #pragma unroll
  for (int w2 = 0; w2 < 4; ++w2) {
    const int u = wtot[w2];
    if (w2 < wave) offtot += u;
    K += u;
  }
  int run = incl - c + offtot;       // kept nodes before n0
  if (t < 200) {
    #pragma unroll
    for (int k = 0; k < 3; ++k) {
      const int n = n0 + k;
      if (k3[k]) { sidx[run] = n; ++run; }
      else       { sidx[K + (n - run)] = n; }
    }
  }
  __syncthreads();

  if (i0 == 0) {
    for (int n = t; n < N_NODES; n += 256)
      mo[b * N_NODES + n] = (n < K) ? 1.0f : 0.0f;
  }

  const float Sd = S + kEps;
  const int kq = K >> 2;             // float4s fully inside [0,K)
  const float* xb  = x  + (size_t)b * N_NODES * C_DIM;
  float*       xob = xo + (size_t)b * N_NODES * C_DIM;
  const float* Ab  = A  + (size_t)b * N_NODES * N_NODES;
  float*       Aob = Ao + (size_t)b * N_NODES * N_NODES;

  for (int ii = wave; ii < ROWTILE; ii += 4) {
    const int i = i0 + ii;
    if (i >= N_NODES) break;
    const int src = sidx[i];

    // ---- x row: xo[b,i,:] = x[b,src,:] * alpha[src] ----
    const float a = sAP[src] / Sd;
    float4 xv = reinterpret_cast<const float4*>(xb + (size_t)src * C_DIM)[lane];
    xv.x *= a; xv.y *= a; xv.z *= a; xv.w *= a;
    reinterpret_cast<float4*>(xob + (size_t)i * C_DIM)[lane] = xv;

    // ---- A row ----
    float4* orow = reinterpret_cast<float4*>(Aob + (size_t)i * N_NODES);
    if (i < K) {
      const float* Arow = Ab + (size_t)src * N_NODES;
      for (int j4 = lane; j4 < NV4; j4 += 64) {
        float4 w4 = {0.f, 0.f, 0.f, 0.f};
        if (j4 < kq) {
          const int j = j4 * 4;
          w4.x = Arow[sidx[j + 0]];
          w4.y = Arow[sidx[j + 1]];
          w4.z = Arow[sidx[j + 2]];
          w4.w = Arow[sidx[j + 3]];
        } else if (j4 == kq) {
          const int j = j4 * 4;
          if (j + 0 < K) w4.x = Arow[sidx[j + 0]];
          if (j + 1 < K) w4.y = Arow[sidx[j + 1]];
          if (j + 2 < K) w4.z = Arow[sidx[j + 2]];
        }
        orow[j4] = w4;
      }
    } else {
      const float4 z = {0.f, 0.f, 0.f, 0.f};
      #pragma unroll 3
      for (int j4 = lane; j4 < NV4; j4 += 64) orow[j4] = z;
    }
  }
}

// ---------------------------------------------------------------------------
extern "C" void kernel_launch(void* const* d_in, const int* in_sizes, int n_in,
                              void* d_out, int out_size, void* d_ws, size_t ws_size,
                              hipStream_t stream) {
  const float* x    = (const float*)d_in[0];
  const float* A    = (const float*)d_in[1];
  const int*   mask = (const int*)d_in[2];
  const float* W    = (const float*)d_in[3];

  const size_t BN = (size_t)B_DIM * N_NODES;

  float* xo = (float*)d_out;                       // (B,N,C)
  float* Ao = xo + BN * C_DIM;                     // (B,N,N)
  float* mo = Ao + BN * N_NODES;                   // (B,N) as 0.0/1.0

  float* alpha_pre = (float*)d_ws;                 // B*N floats

  k_scores<<<SBLOCKS, 256, 0, stream>>>(x, W, mask, alpha_pre);
  k_gather<<<GBLOCKS, 256, 0, stream>>>(x, A, alpha_pre, xo, Ao, mo);
}